// Round 7
// baseline (45.811 us; speedup 1.0000x reference)
//
#include <hip/hip_runtime.h>
#include <math.h>

#define LEN       16384
#define NTHREADS  1024
#define SEG       16          // LEN / NTHREADS
#define NWAVES    16

// exp(-1/20) and derived constants (double-precision values)
#define DECAY_F 0.951229424500714f      // d = exp(-0.05)
#define D16_F   0.449328964117222f      // d^16 = exp(-0.8)
#define G16_F   7.5886329f              // sum_{i=1..16} d^(2i)

// Full XOR swizzle (word granularity): conflict-free reads (2 lanes/bank),
// 2-way writes (free). XOR touches only bits 0..4 -> stays inside each wave's
// private 1024-word chunk (wave-sync safe). 0 conflicts verified r1/r2/r5.
__device__ __forceinline__ int swz(int a) { return a ^ ((a >> 5) & 31); }

// one scan step: s = d*s + x; A += s^2; Bc += d^(i+1)*s  (ww constant-folds)
#define STEP(xv) { s = __builtin_fmaf(DECAY_F, s, (xv)); ww *= DECAY_F; \
                   A = __builtin_fmaf(s, s, A); Bc = __builtin_fmaf(ww, s, Bc); }

// diff of one float4 pair -> swizzled LDS
#define DSW(base4, A4, B4) { const int _b = (base4) * 4; \
    smem[swz(_b + 0)] = (A4).x - (B4).x; smem[swz(_b + 1)] = (A4).y - (B4).y; \
    smem[swz(_b + 2)] = (A4).z - (B4).z; smem[swz(_b + 3)] = (A4).w - (B4).w; }

__global__ __launch_bounds__(NTHREADS) void vr_fused(
    const float* __restrict__ in, const float* __restrict__ tgt,
    float* __restrict__ accum, unsigned int* __restrict__ counter,
    float* __restrict__ out, int nblocks)
{
    __shared__ float smem[LEN];                 // 64 KiB -> 2 blocks/CU
    __shared__ float wa[NWAVES], wb[NWAVES], red[NWAVES];

    const int tid  = threadIdx.x;
    const int lane = tid & 63;
    const int wid  = tid >> 6;
    // Wave-private chunk: wave w owns words [1024w, 1024w+1024).
    const int cb4 = (wid << 8) + lane;          // float4 index base

    const long long rb = (long long)blockIdx.x * LEN;
    const float4* __restrict__ in4 = (const float4*)(in  + rb);
    const float4* __restrict__ tg4 = (const float4*)(tgt + rb);

    // ---- phase 1a: 8 independent coalesced float4 loads ----
    const float4 a0 = in4[cb4];       const float4 b0 = tg4[cb4];
    const float4 a1 = in4[cb4 +  64]; const float4 b1 = tg4[cb4 +  64];
    const float4 a2 = in4[cb4 + 128]; const float4 b2 = tg4[cb4 + 128];
    const float4 a3 = in4[cb4 + 192]; const float4 b3 = tg4[cb4 + 192];
    __builtin_amdgcn_sched_barrier(0);

    // ---- phase 1b: diff -> swizzled LDS (stays inside own wave chunk) ----
    DSW(cb4,       a0, b0)
    DSW(cb4 +  64, a1, b1)
    DSW(cb4 + 128, a2, b2)
    DSW(cb4 + 192, a3, b3)
    // Wave-local sync: producer lanes == consumer wave; no block barrier.
    asm volatile("s_waitcnt lgkmcnt(0)" ::: "memory");
    __builtin_amdgcn_sched_barrier(0);

    // ---- phase 2: per-thread local scan + moments (segment = tid) ----
    // s_i from zero carry; true y_i = s_i + d^(i+1)*c.
    // sum y^2 = A + 2c*Bc + c^2*G16.
    float s = 0.f, A = 0.f, Bc = 0.f, ww = 1.f;
    const int base = tid * SEG;
    #pragma unroll
    for (int i = 0; i < SEG; ++i) {
        const float x = smem[swz(base + i)];
        STEP(x)
    }

    // ---- affine scan of carries: f(c) = a*c + b, low->high ----
    float aa = D16_F, bb = s;
    #pragma unroll
    for (int j = 1; j < 64; j <<= 1) {
        const float au = __shfl_up(aa, j);
        const float bu = __shfl_up(bb, j);
        if (lane >= j) {
            bb = __builtin_fmaf(aa, bu, bb);
            aa *= au;
        }
    }
    if (lane == 63) { wa[wid] = aa; wb[wid] = bb; }
    __syncthreads();

    // carry entering this wave, then this thread
    float C = 0.f;
    for (int k = 0; k < wid; ++k) C = __builtin_fmaf(wa[k], C, wb[k]);
    float aex = __shfl_up(aa, 1);
    float bex = __shfl_up(bb, 1);
    if (lane == 0) { aex = 1.f; bex = 0.f; }
    const float c = __builtin_fmaf(aex, C, bex);

    float part = A + 2.f * c * Bc + (c * c) * G16_F;

    // ---- block reduce (deterministic within block) ----
    #pragma unroll
    for (int j = 32; j > 0; j >>= 1) part += __shfl_down(part, j);
    if (lane == 0) red[wid] = part;
    __syncthreads();

    if (tid == 0) {
        float t = 0.f;
        #pragma unroll
        for (int k = 0; k < NWAVES; ++k) t += red[k];

        // Relaxed device-scope RMW at the coherence point (cross-XCD safe).
        // NO release/acquire -> no L2 writeback/invalidate (the r4 disaster).
        const float old_acc = atomicAdd(accum, t);
        // Ack-order: our accum-add must reach the coherence point before our
        // counter-add does. vmcnt wait = ack only, no cache maintenance.
        asm volatile("s_waitcnt vmcnt(0)" :: "v"(old_acc) : "memory");
        const unsigned int old = atomicAdd(counter, 1u);
        if (old == (unsigned int)(nblocks - 1)) {
            // All 1024 accum-adds are at the coherence point; read the total.
            const float total = atomicAdd(accum, 0.0f);
            out[0] = sqrtf(total * 0.05f);   // sqrt((1/TAU) * sum * DT)
        }
    }
}

extern "C" void kernel_launch(void* const* d_in, const int* in_sizes, int n_in,
                              void* d_out, int out_size, void* d_ws, size_t ws_size,
                              hipStream_t stream) {
    const float* in  = (const float*)d_in[0];
    const float* tgt = (const float*)d_in[1];
    float* out = (float*)d_out;
    float* accum = (float*)d_ws;                   // ws[0] = running sum
    unsigned int* counter = (unsigned int*)d_ws + 1; // ws[1] = done counter
    const int rows = in_sizes[0] / LEN;            // 1024

    // zero accum+counter each call (8-byte graph-capturable memset node)
    hipMemsetAsync(d_ws, 0, 2 * sizeof(float), stream);
    vr_fused<<<dim3(rows), dim3(NTHREADS), 0, stream>>>(
        in, tgt, accum, counter, out, rows);
}

// Round 8
// 27.246 us; speedup vs baseline: 1.6814x; 1.6814x over previous
//
#include <hip/hip_runtime.h>
#include <math.h>

#define LEN       16384
#define NTHREADS  512
#define SEG       32          // LEN / NTHREADS
#define NWAVES    8

// exp(-1/20) and derived constants (double-precision values)
#define DECAY_F 0.951229424500714f      // d = exp(-0.05)
#define D32_F   0.20189651799465538f    // d^32 = exp(-1.6)
#define G32_F   9.1207513f              // sum_{i=1..32} d^(2i)

// Full XOR swizzle: phase-2 read addr = 32*t + i -> bank (i ^ (t&31)):
// 32 distinct banks across 64 lanes, 2 lanes/bank = conflict-free.
__device__ __forceinline__ int swz(int a) { return a ^ ((a >> 5) & 31); }

__global__ __launch_bounds__(NTHREADS) void vr_main(
    const float* __restrict__ in, const float* __restrict__ tgt,
    float* __restrict__ partial)
{
    __shared__ float smem[LEN];                 // 64 KiB
    __shared__ float wa[NWAVES], wb[NWAVES], red[NWAVES];

    const int row = blockIdx.x;
    const int tid = threadIdx.x;
    const long long rb = (long long)row * LEN;
    const float4* __restrict__ in4 = (const float4*)(in  + rb);
    const float4* __restrict__ tg4 = (const float4*)(tgt + rb);

    // ---- phase 1: coalesced float4 loads, diff -> swizzled LDS ----
    #pragma unroll
    for (int p = 0; p < LEN / 4 / NTHREADS; ++p) {
        const int idx4 = tid + p * NTHREADS;
        const float4 a = in4[idx4];
        const float4 b = tg4[idx4];
        const int base = idx4 * 4;
        smem[swz(base + 0)] = a.x - b.x;
        smem[swz(base + 1)] = a.y - b.y;
        smem[swz(base + 2)] = a.z - b.z;
        smem[swz(base + 3)] = a.w - b.w;
    }
    __syncthreads();

    // ---- phase 2: per-thread local scan + moments ----
    // s_i: local scan from 0.  True y_i = s_i + d^(i+1) * c (c = carry-in).
    // sum y_i^2 = A + 2c*B + c^2*G,  A=sum s^2, B=sum d^(i+1) s_i.
    float s = 0.f, A = 0.f, Bc = 0.f, w = 1.f;
    const int base = tid * SEG;
    #pragma unroll
    for (int i = 0; i < SEG; ++i) {
        const float x = smem[swz(base + i)];
        s = __builtin_fmaf(DECAY_F, s, x);
        w *= DECAY_F;                           // constant-folds to d^(i+1)
        A  = __builtin_fmaf(s, s, A);
        Bc = __builtin_fmaf(w, s, Bc);
    }

    // ---- affine scan of carries: f_t(c) = a*c + b, compose low->high ----
    float a = D32_F;    // d^SEG
    float b = s;        // segment end value from zero carry
    const int lane = tid & 63;
    #pragma unroll
    for (int j = 1; j < 64; j <<= 1) {
        const float au = __shfl_up(a, j);
        const float bu = __shfl_up(b, j);
        if (lane >= j) {
            b = __builtin_fmaf(a, bu, b);       // self o lower
            a *= au;
        }
    }
    const int wid = tid >> 6;
    if (lane == 63) { wa[wid] = a; wb[wid] = b; }
    __syncthreads();

    // carry entering this wave (scan 0..wid-1 wave aggregates; LDS broadcast)
    float C = 0.f;
    for (int k = 0; k < wid; ++k) C = __builtin_fmaf(wa[k], C, wb[k]);
    // exclusive intra-wave aggregate
    float aex = __shfl_up(a, 1);
    float bex = __shfl_up(b, 1);
    if (lane == 0) { aex = 1.f; bex = 0.f; }
    const float c = __builtin_fmaf(aex, C, bex);   // carry into this thread

    float part = A + 2.f * c * Bc + (c * c) * G32_F;

    // ---- block reduce (deterministic), write per-row partial ----
    #pragma unroll
    for (int j = 32; j > 0; j >>= 1) part += __shfl_down(part, j);
    if (lane == 0) red[wid] = part;
    __syncthreads();
    if (tid == 0) {
        float t = 0.f;
        #pragma unroll
        for (int k = 0; k < NWAVES; ++k) t += red[k];
        partial[row] = t;
    }
}

__global__ __launch_bounds__(1024) void vr_final(
    const float* __restrict__ partial, int n, float* __restrict__ out)
{
    __shared__ float red[16];
    const int tid = threadIdx.x;
    float v = 0.f;
    for (int k = tid; k < n; k += 1024) v += partial[k];
    #pragma unroll
    for (int j = 32; j > 0; j >>= 1) v += __shfl_down(v, j);
    const int lane = tid & 63, wid = tid >> 6;
    if (lane == 0) red[wid] = v;
    __syncthreads();
    if (tid == 0) {
        float t = 0.f;
        #pragma unroll
        for (int k = 0; k < 16; ++k) t += red[k];
        out[0] = sqrtf(t * 0.05f);   // sqrt((1/TAU) * sum * DT)
    }
}

extern "C" void kernel_launch(void* const* d_in, const int* in_sizes, int n_in,
                              void* d_out, int out_size, void* d_ws, size_t ws_size,
                              hipStream_t stream) {
    const float* in  = (const float*)d_in[0];
    const float* tgt = (const float*)d_in[1];
    float* out = (float*)d_out;
    float* ws  = (float*)d_ws;          // rows floats of scratch (4 KiB)
    const int rows = in_sizes[0] / LEN; // 1024

    vr_main<<<dim3(rows), dim3(NTHREADS), 0, stream>>>(in, tgt, ws);
    vr_final<<<dim3(1), dim3(1024), 0, stream>>>(ws, rows, out);
}